// Round 6
// baseline (171.467 us; speedup 1.0000x reference)
//
#include <hip/hip_runtime.h>
#include <hip/hip_bf16.h>
#include <math.h>

// SDGCN fused, v6: barrier-free main loop. K/V fragments are read directly
// from the pre-split global planes (per-lane b128, L1/L2-served) instead of
// LDS staging -> no __syncthreads in the k-loop, waves desynchronize and
// pipes overlap. Merge + epilogue identical to v5 (verified).
//
// mfma_f32_32x32x16_bf16 layouts (m74/m101-verified C/D; standard A/B):
//   A-frag: lane l holds A[l&31][(l>>5)*8+e]
//   B-frag: lane l holds B[(l>>5)*8+e][l&31]
//   C/D:    lane l, reg r holds C[(r&3)+8*(r>>2)+4*(l>>5)][l&31]

typedef short bf16x8 __attribute__((ext_vector_type(8)));
typedef float f32x4  __attribute__((ext_vector_type(4)));
typedef float f32x16 __attribute__((ext_vector_type(16)));
typedef int   i32x4  __attribute__((ext_vector_type(4)));

constexpr int kN = 1024;
constexpr int kD = 64;
constexpr size_t kPlane = 48u * 1024u * 64u;

#define MFMA32(a,b,c) __builtin_amdgcn_mfma_f32_32x32x16_bf16((a),(b),(c),0,0,0)
#define MFMA16(a,b,c) __builtin_amdgcn_mfma_f32_16x16x32_bf16((a),(b),(c),0,0,0)

__device__ __forceinline__ void splitv(float v, short& h, short& l) {
  unsigned u = __float_as_uint(v);
  h = (short)(u >> 16);
  float hf = __uint_as_float(u & 0xFFFF0000u);
  l = (short)(__float_as_uint(v - hf) >> 16);
}

__device__ __forceinline__ unsigned pkbf(float a, float b) {
  return (__float_as_uint(a) >> 16) | (__float_as_uint(b) & 0xFFFF0000u);
}

// ---------------- pre-pass (v4-verified): X -> bf16 hi/lo planes ----------
__global__ __launch_bounds__(256)
void presplit(const float* __restrict__ X, short* __restrict__ Xh,
              short* __restrict__ Xl, short* __restrict__ XTh,
              short* __restrict__ XTl)
{
  __shared__ short Sh[64][68], Sl[64][68];
  const int t  = threadIdx.x;
  const int bt = blockIdx.x >> 4;
  const int mb = blockIdx.x & 15;
  const size_t base = (size_t)bt * 65536 + (size_t)mb * 64 * 64;

#pragma unroll
  for (int k = 0; k < 4; ++k) {
    int idx = t + k * 256;
    int row = idx >> 4;
    int c4  = (idx & 15) * 4;
    float4 v = *(const float4*)(X + base + row * 64 + c4);
    short h0,l0,h1,l1,h2,l2,h3,l3;
    splitv(v.x, h0, l0); splitv(v.y, h1, l1);
    splitv(v.z, h2, l2); splitv(v.w, h3, l3);
    short4 hv = make_short4(h0, h1, h2, h3);
    short4 lv = make_short4(l0, l1, l2, l3);
    *(short4*)(Xh + base + row * 64 + c4) = hv;
    *(short4*)(Xl + base + row * 64 + c4) = lv;
    *(short4*)&Sh[row][c4] = hv;
    *(short4*)&Sl[row][c4] = lv;
  }
  __syncthreads();

  const size_t tbase = (size_t)bt * 65536 + (size_t)mb * 64;
#pragma unroll
  for (int k = 0; k < 2; ++k) {
    int idx = t + k * 256;
    int d   = idx >> 3;
    int m8  = (idx & 7) * 8;
    bf16x8 hv, lv;
#pragma unroll
    for (int j = 0; j < 8; ++j) { hv[j] = Sh[m8 + j][d]; lv[j] = Sl[m8 + j][d]; }
    *(bf16x8*)(XTh + tbase + (size_t)d * 1024 + m8) = hv;
    *(bf16x8*)(XTl + tbase + (size_t)d * 1024 + m8) = lv;
  }
}

// ---------------- main fused kernel ----------------
__global__ __launch_bounds__(256)
void sdgcn_v6(const float* __restrict__ X, const float* __restrict__ A,
              const float* __restrict__ W, const float* __restrict__ gamma,
              const float* __restrict__ beta, float* __restrict__ out,
              const short* __restrict__ Xh, const short* __restrict__ Xl,
              const short* __restrict__ XTh, const short* __restrict__ XTl)
{
  __shared__ __align__(16) float Har[64 * 68];   // merge / epilogue exchange
  __shared__ float aM[128], aZ[128], aF[192];    // stats: m, Z, {fa,fb,1/(8Z)}

  const int t    = threadIdx.x;
  const int wave = t >> 6;
  const int lane = t & 63;
  const int kg   = wave >> 1;      // k-group 0/1 (512 k each)
  const int qw   = wave & 1;       // q-wave 0/1 (32 rows each)
  const int half = lane >> 5;      // 0/1
  const int l31  = lane & 31;
  const int bt   = blockIdx.x >> 4;
  const int qt   = blockIdx.x & 15;
  const int qblk = qt * 64;
  const size_t xb = (size_t)bt * 65536;

  // ---- Q B-frags: lane holds Q[qblk+qw*32+l31][16c + half*8 + e]
  const int qmine = qblk + qw * 32 + l31;
  bf16x8 qh[4], qlo[4];
#pragma unroll
  for (int c = 0; c < 4; ++c) {
    const size_t off = xb + (size_t)qmine * kD + 16 * c + half * 8;
    qh[c]  = *(const bf16x8*)(Xh + off);
    qlo[c] = *(const bf16x8*)(Xl + off);
  }

  f32x16 o0, o1;
#pragma unroll
  for (int r = 0; r < 16; ++r) { o0[r] = 0.f; o1[r] = 0.f; }
  float mrun = -INFINITY, Z = 0.f;

  for (int ks = 0; ks < 16; ++ks) {
    const int kb = kg * 512 + ks * 32;

    // A gate values: agv[4j+i] = A[qmine][kb + 8j + 4*half + i]
    const float* Arow = A + (size_t)qmine * kN + kb + 4 * half;
    float4 ag0 = *(const float4*)(Arow);
    float4 ag1 = *(const float4*)(Arow + 8);
    float4 ag2 = *(const float4*)(Arow + 16);
    float4 ag3 = *(const float4*)(Arow + 24);
    float agv[16] = {ag0.x,ag0.y,ag0.z,ag0.w, ag1.x,ag1.y,ag1.z,ag1.w,
                     ag2.x,ag2.y,ag2.z,ag2.w, ag3.x,ag3.y,ag3.z,ag3.w};

    // ---- QK^T swapped, K-frags direct from global planes.
    // A-frag: lane holds K[kb + l31][16c + 8*half + e]; two acc chains.
    const short* Khp = Xh + xb + (size_t)(kb + l31) * kD + 8 * half;
    const short* Klp = Xl + xb + (size_t)(kb + l31) * kD + 8 * half;
    f32x16 sa, sb;
#pragma unroll
    for (int r = 0; r < 16; ++r) { sa[r] = 0.f; sb[r] = 0.f; }
#pragma unroll
    for (int c = 0; c < 2; ++c) {
      bf16x8 kh = *(const bf16x8*)(Khp + 16 * c);
      bf16x8 kl = *(const bf16x8*)(Klp + 16 * c);
      sa = MFMA32(kh, qh[c],  sa);
      sa = MFMA32(kh, qlo[c], sa);
      sa = MFMA32(kl, qh[c],  sa);
    }
#pragma unroll
    for (int c = 2; c < 4; ++c) {
      bf16x8 kh = *(const bf16x8*)(Khp + 16 * c);
      bf16x8 kl = *(const bf16x8*)(Klp + 16 * c);
      sb = MFMA32(kh, qh[c],  sb);
      sb = MFMA32(kh, qlo[c], sb);
      sb = MFMA32(kl, qh[c],  sb);
    }
#pragma unroll
    for (int r = 0; r < 16; ++r) sa[r] += sb[r];

    // ---- defer-max online softmax (stats lane-local, q = l31)
    float sm = sa[0];
#pragma unroll
    for (int r = 1; r < 16; ++r) sm = fmaxf(sm, sa[r]);
    sm = fmaxf(sm, __shfl_xor(sm, 32, 64));
    if (__any(sm > mrun + 8.f)) {
      const float nm = fmaxf(mrun, sm);
      const float f  = __expf(mrun - nm);   // 0 on first tile
      mrun = nm; Z *= f;
#pragma unroll
      for (int r = 0; r < 16; ++r) {
        const float fr = __shfl(f, (r & 3) + 8 * (r >> 2) + 4 * half, 64);
        o0[r] *= fr; o1[r] *= fr;
      }
    }
    float zt = 0.f;
    float pa[16];
#pragma unroll
    for (int r = 0; r < 16; ++r) {
      const float pv = __expf(sa[r] - mrun);
      zt += pv;
      pa[r] = pv * agv[r];
    }
    zt += __shfl_xor(zt, 32, 64);
    Z += zt;

    // ---- pack gated P to bf16 + cross-half exchange -> PV A-frags
    unsigned du[8], su[8];
#pragma unroll
    for (int j = 0; j < 8; ++j) du[j] = pkbf(pa[2*j], pa[2*j+1]);
#pragma unroll
    for (int j = 0; j < 8; ++j) su[j] = (unsigned)__shfl_xor((int)du[j], 32, 64);
    const bool lo = (half == 0);
    i32x4 w0, w1;
    w0[0] = lo ? du[0] : su[2]; w0[1] = lo ? du[1] : su[3];
    w0[2] = lo ? su[0] : du[2]; w0[3] = lo ? su[1] : du[3];
    w1[0] = lo ? du[4] : su[6]; w1[1] = lo ? du[5] : su[7];
    w1[2] = lo ? su[4] : du[6]; w1[3] = lo ? su[5] : du[7];
    bf16x8 pf0 = *(bf16x8*)&w0;   // k-chunk 0 (k=0..15)
    bf16x8 pf1 = *(bf16x8*)&w1;   // k-chunk 1 (k=16..31)

    // ---- PV, V B-frags direct from transposed planes.
    // B-frag: lane holds V[kb + kchunk*16 + 8*half + e][d], d = l31 (+32 for o1)
    {
      const short* Vhp = XTh + xb + (size_t)l31 * 1024 + kb + 8 * half;
      const short* Vlp = XTl + xb + (size_t)l31 * 1024 + kb + 8 * half;
      bf16x8 vh, vl;
      vh = *(const bf16x8*)(Vhp);
      vl = *(const bf16x8*)(Vlp);
      o0 = MFMA32(pf0, vh, o0); o0 = MFMA32(pf0, vl, o0);
      vh = *(const bf16x8*)(Vhp + 16);
      vl = *(const bf16x8*)(Vlp + 16);
      o0 = MFMA32(pf1, vh, o0); o0 = MFMA32(pf1, vl, o0);
      vh = *(const bf16x8*)(Vhp + 32 * 1024);
      vl = *(const bf16x8*)(Vlp + 32 * 1024);
      o1 = MFMA32(pf0, vh, o1); o1 = MFMA32(pf0, vl, o1);
      vh = *(const bf16x8*)(Vhp + 32 * 1024 + 16);
      vl = *(const bf16x8*)(Vlp + 32 * 1024 + 16);
      o1 = MFMA32(pf1, vh, o1); o1 = MFMA32(pf1, vl, o1);
    }
  }

  // ================= split-K merge (v5-verified) =================
  if (lane < 32) {
    aM[kg * 64 + qw * 32 + l31] = mrun;
    aZ[kg * 64 + qw * 32 + l31] = Z;
  }
  if (kg == 1) {   // group B parks its O in Har
#pragma unroll
    for (int r = 0; r < 16; ++r) {
      const int qq = qw * 32 + (r & 3) + 8 * (r >> 2) + 4 * half;
      Har[qq * 68 + l31]      = o0[r];
      Har[qq * 68 + l31 + 32] = o1[r];
    }
  }
  __syncthreads();
  if (kg == 1 && lane < 32) {
    const int q = qw * 32 + l31;
    const float ma = aM[q], mb = mrun;
    const float m  = fmaxf(ma, mb);
    const float fa = __expf(ma - m), fb = __expf(mb - m);
    const float Zs = aZ[q] * fa + Z * fb;
    aF[q]       = fa;
    aF[64 + q]  = fb;
    aF[128 + q] = 1.0f / (8.0f * Zs);   // sqrt(64)=8
  }
  __syncthreads();
  if (kg == 0) {
#pragma unroll
    for (int r = 0; r < 16; ++r) {
      const int qq = qw * 32 + (r & 3) + 8 * (r >> 2) + 4 * half;
      const float fa = aF[qq], fb = aF[64 + qq];
      Har[qq * 68 + l31]      = o0[r] * fa + Har[qq * 68 + l31]      * fb;
      Har[qq * 68 + l31 + 32] = o1[r] * fa + Har[qq * 68 + l31 + 32] * fb;
    }
  }
  __syncthreads();

  // ================= epilogue (v2-verified 16x16 path, 16 rows/wave) ======
  const int g  = lane >> 4;
  const int ql = lane & 15;
  const int er = wave * 16;
  const float i8z = aF[128 + er + ql];

  bf16x8 hh[2], hl[2];
#pragma unroll
  for (int kk = 0; kk < 2; ++kk) {
    const float* hp = &Har[(er + ql) * 68 + kk * 32 + g * 8];
    float4 v0 = *(const float4*)hp;
    float4 v1 = *(const float4*)(hp + 4);
    float v[8] = {v0.x*i8z, v0.y*i8z, v0.z*i8z, v0.w*i8z,
                  v1.x*i8z, v1.y*i8z, v1.z*i8z, v1.w*i8z};
#pragma unroll
    for (int e = 0; e < 8; ++e) { short a, b; splitv(v[e], a, b); hh[kk][e] = a; hl[kk][e] = b; }
  }

  f32x4 lin[4];
#pragma unroll
  for (int c = 0; c < 4; ++c) {
    bf16x8 wh[2], wl[2];
#pragma unroll
    for (int kk = 0; kk < 2; ++kk) {
      const float* wp = W + (size_t)(c * 16 + ql) * kD + kk * 32 + g * 8;
      float4 v0 = *(const float4*)wp;
      float4 v1 = *(const float4*)(wp + 4);
      float v[8] = {v0.x, v0.y, v0.z, v0.w, v1.x, v1.y, v1.z, v1.w};
#pragma unroll
      for (int e = 0; e < 8; ++e) { short a, b; splitv(v[e], a, b); wh[kk][e] = a; wl[kk][e] = b; }
    }
    f32x4 acc = {0.f, 0.f, 0.f, 0.f};
    acc = MFMA16(hh[0], wh[0], acc);
    acc = MFMA16(hh[1], wh[1], acc);
    acc = MFMA16(hh[0], wl[0], acc);
    acc = MFMA16(hh[1], wl[1], acc);
    acc = MFMA16(hl[0], wh[0], acc);
    acc = MFMA16(hl[1], wh[1], acc);
    lin[c] = acc;
  }

  float rl[4][4];
#pragma unroll
  for (int c = 0; c < 4; ++c)
#pragma unroll
    for (int r = 0; r < 4; ++r) rl[c][r] = fmaxf(lin[c][r], 0.f);

  float mu[4], rstd[4];
#pragma unroll
  for (int r = 0; r < 4; ++r) {
    float s1 = rl[0][r] + rl[1][r] + rl[2][r] + rl[3][r];
    float s2 = rl[0][r]*rl[0][r] + rl[1][r]*rl[1][r] + rl[2][r]*rl[2][r] + rl[3][r]*rl[3][r];
#pragma unroll
    for (int off = 1; off < 16; off <<= 1) {
      s1 += __shfl_xor(s1, off, 64);
      s2 += __shfl_xor(s2, off, 64);
    }
    mu[r] = s1 * (1.f / 64.f);
    const float var = s2 * (1.f / 64.f) - mu[r] * mu[r];
    rstd[r] = rsqrtf(var + 1e-5f);
  }

#pragma unroll
  for (int c = 0; c < 4; ++c) {
    const float gm = gamma[c * 16 + ql];
    const float bb = beta[c * 16 + ql];
#pragma unroll
    for (int r = 0; r < 4; ++r) {
      const int qrow = qblk + er + 4 * g + r;
      const size_t off = ((size_t)bt * kN + qrow) * kD + c * 16 + ql;
      out[off] = (rl[c][r] - mu[r]) * rstd[r] * gm + bb + X[off];
    }
  }
}

extern "C" void kernel_launch(void* const* d_in, const int* in_sizes, int n_in,
                              void* d_out, int out_size, void* d_ws, size_t ws_size,
                              hipStream_t stream) {
  const float* X     = (const float*)d_in[0];
  const float* A     = (const float*)d_in[1];
  const float* W     = (const float*)d_in[2];
  const float* gamma = (const float*)d_in[3];
  const float* beta  = (const float*)d_in[4];
  float* out = (float*)d_out;

  short* Xh  = (short*)d_ws;
  short* Xl  = Xh  + kPlane;
  short* XTh = Xl  + kPlane;
  short* XTl = XTh + kPlane;

  presplit<<<dim3(48 * 16), 256, 0, stream>>>(X, Xh, Xl, XTh, XTl);
  sdgcn_v6<<<dim3(48 * 16), 256, 0, stream>>>(X, A, W, gamma, beta, out,
                                              Xh, Xl, XTh, XTl);
}

// Round 7
// 81.784 us; speedup vs baseline: 2.0966x; 2.0966x over previous
//
#include <hip/hip_runtime.h>
#include <hip/hip_bf16.h>
#include <math.h>

// SDGCN fused, v7 = v5 (verified, 81.7us) + pre-arranged A-gate fragments.
// v5's A-gate loads were the only divergent global access in the k-loop
// (64 lanes x 32 rows x 4KB stride = ~32 lines/instr). prearr_A reorders A
// once into per-(step,wave,lane) order so the k-loop reads are coalesced
// float4s. Template fallback to the v5 direct-A path if ws is too small.
//
// mfma_f32_32x32x16_bf16 layouts (m74/m101-verified C/D; standard A/B):
//   A-frag: lane l holds A[l&31][(l>>5)*8+e]
//   B-frag: lane l holds B[(l>>5)*8+e][l&31]
//   C/D:    lane l, reg r holds C[(r&3)+8*(r>>2)+4*(l>>5)][l&31]

typedef short bf16x8 __attribute__((ext_vector_type(8)));
typedef float f32x4  __attribute__((ext_vector_type(4)));
typedef float f32x16 __attribute__((ext_vector_type(16)));
typedef int   i32x4  __attribute__((ext_vector_type(4)));

constexpr int kN = 1024;
constexpr int kD = 64;
constexpr size_t kPlane = 48u * 1024u * 64u;
constexpr size_t kAfFloats = 16u * 32u * 2u * 1024u;   // 4MB

#define MFMA32(a,b,c) __builtin_amdgcn_mfma_f32_32x32x16_bf16((a),(b),(c),0,0,0)
#define MFMA16(a,b,c) __builtin_amdgcn_mfma_f32_16x16x32_bf16((a),(b),(c),0,0,0)

__device__ __forceinline__ void splitv(float v, short& h, short& l) {
  unsigned u = __float_as_uint(v);
  h = (short)(u >> 16);
  float hf = __uint_as_float(u & 0xFFFF0000u);
  l = (short)(__float_as_uint(v - hf) >> 16);
}

__device__ __forceinline__ unsigned pkbf(float a, float b) {
  return (__float_as_uint(a) >> 16) | (__float_as_uint(b) & 0xFFFF0000u);
}

// ---------------- pre-pass 1 (v4-verified): X -> bf16 hi/lo planes --------
__global__ __launch_bounds__(256)
void presplit(const float* __restrict__ X, short* __restrict__ Xh,
              short* __restrict__ Xl, short* __restrict__ XTh,
              short* __restrict__ XTl)
{
  __shared__ short Sh[64][68], Sl[64][68];
  const int t  = threadIdx.x;
  const int bt = blockIdx.x >> 4;
  const int mb = blockIdx.x & 15;
  const size_t base = (size_t)bt * 65536 + (size_t)mb * 64 * 64;

#pragma unroll
  for (int k = 0; k < 4; ++k) {
    int idx = t + k * 256;
    int row = idx >> 4;
    int c4  = (idx & 15) * 4;
    float4 v = *(const float4*)(X + base + row * 64 + c4);
    short h0,l0,h1,l1,h2,l2,h3,l3;
    splitv(v.x, h0, l0); splitv(v.y, h1, l1);
    splitv(v.z, h2, l2); splitv(v.w, h3, l3);
    short4 hv = make_short4(h0, h1, h2, h3);
    short4 lv = make_short4(l0, l1, l2, l3);
    *(short4*)(Xh + base + row * 64 + c4) = hv;
    *(short4*)(Xl + base + row * 64 + c4) = lv;
    *(short4*)&Sh[row][c4] = hv;
    *(short4*)&Sl[row][c4] = lv;
  }
  __syncthreads();

  const size_t tbase = (size_t)bt * 65536 + (size_t)mb * 64;
#pragma unroll
  for (int k = 0; k < 2; ++k) {
    int idx = t + k * 256;
    int d   = idx >> 3;
    int m8  = (idx & 7) * 8;
    bf16x8 hv, lv;
#pragma unroll
    for (int j = 0; j < 8; ++j) { hv[j] = Sh[m8 + j][d]; lv[j] = Sl[m8 + j][d]; }
    *(bf16x8*)(XTh + tbase + (size_t)d * 1024 + m8) = hv;
    *(bf16x8*)(XTl + tbase + (size_t)d * 1024 + m8) = lv;
  }
}

// ---------------- pre-pass 2: A -> per-lane fragment order ----------------
// Af[qt][gks][qw] is a 4KB block: [j 0..3][lane 0..63][e 0..3] f32, holding
// A[qt*64 + qw*32 + (lane&31)][gks*32 + e + 8j + 4*(lane>>5)].
__global__ __launch_bounds__(256)
void prearr_A(const float* __restrict__ A, float* __restrict__ Af)
{
  const int qt = blockIdx.x >> 5;
  const int ks = blockIdx.x & 31;
  const int t  = threadIdx.x;
  float* dst = Af + ((size_t)(qt * 32 + ks) * 2048);
#pragma unroll
  for (int s = t; s < 512; s += 256) {
    const int qw = s >> 8, j = (s >> 6) & 3, lane = s & 63;
    const int q = qt * 64 + qw * 32 + (lane & 31);
    const int k = ks * 32 + 8 * j + 4 * (lane >> 5);
    float4 v = *(const float4*)(A + (size_t)q * kN + k);
    *(float4*)(dst + s * 4) = v;
  }
}

// ---------------- main fused kernel ----------------
template<int AMODE>
__global__ __launch_bounds__(256)
void sdgcn_v7(const float* __restrict__ X, const float* __restrict__ A,
              const float* __restrict__ W, const float* __restrict__ gamma,
              const float* __restrict__ beta, float* __restrict__ out,
              const short* __restrict__ Xh, const short* __restrict__ Xl,
              const short* __restrict__ XTh, const short* __restrict__ XTl,
              const float* __restrict__ Af)
{
  __shared__ __align__(16) unsigned char LB[38912];

  const int t    = threadIdx.x;
  const int wave = t >> 6;
  const int lane = t & 63;
  const int kg   = wave >> 1;      // k-group 0/1
  const int qw   = wave & 1;       // q-wave 0/1 (32 rows each)
  const int half = lane >> 5;      // 0/1
  const int l31  = lane & 31;
  const int bt   = blockIdx.x >> 4;
  const int qt   = blockIdx.x & 15;
  const int qblk = qt * 64;
  const size_t xb = (size_t)bt * 65536;

  short* Khg  = (short*)(LB + kg * 9216);
  short* Klg  = Khg + 2304;
  short* Vthg = (short*)(LB + 18432 + kg * 10240);
  short* Vtlg = Vthg + 2560;
  float* Har  = (float*)(LB + 18432);   // [64][68]
  float* aM   = (float*)LB;             // [2][64]
  float* aZ   = aM + 128;
  float* aF   = aZ + 128;               // [3][64]

  // ---- Q B-frags
  const int qmine = qblk + qw * 32 + l31;
  bf16x8 qh[4], qlo[4];
#pragma unroll
  for (int c = 0; c < 4; ++c) {
    const size_t off = xb + (size_t)qmine * kD + 16 * c + half * 8;
    qh[c]  = *(const bf16x8*)(Xh + off);
    qlo[c] = *(const bf16x8*)(Xl + off);
  }

  f32x16 o0, o1;
#pragma unroll
  for (int r = 0; r < 16; ++r) { o0[r] = 0.f; o1[r] = 0.f; }
  float mrun = -INFINITY, Z = 0.f;

  const int tg = t & 127;

  auto ldK = [&](int kb, int j, bf16x8& h, bf16x8& l) {
    int ck = tg + 128 * j; int kr = ck >> 3; int kc = (ck & 7) * 8;
    size_t off = xb + (size_t)(kb + kr) * kD + kc;
    h = *(const bf16x8*)(Xh + off);
    l = *(const bf16x8*)(Xl + off);
  };
  auto ldV = [&](int kb, int j, bf16x8& h, bf16x8& l) {
    int cv = tg + 128 * j; int vd = cv >> 2; int vm = (cv & 3) * 8;
    size_t off = xb + (size_t)vd * 1024 + kb + vm;
    h = *(const bf16x8*)(XTh + off);
    l = *(const bf16x8*)(XTl + off);
  };
  auto stK = [&](int j, bf16x8 h, bf16x8 l) {
    int ck = tg + 128 * j; int kr = ck >> 3; int kc = (ck & 7) * 8;
    *(bf16x8*)&Khg[kr * 72 + kc] = h;
    *(bf16x8*)&Klg[kr * 72 + kc] = l;
  };
  auto stV = [&](int j, bf16x8 h, bf16x8 l) {
    int cv = tg + 128 * j; int vd = cv >> 2; int vm = (cv & 3) * 8;
    *(bf16x8*)&Vthg[vd * 40 + vm] = h;
    *(bf16x8*)&Vtlg[vd * 40 + vm] = l;
  };

  // prologue: stage first tile of this k-group
  {
    bf16x8 a0,a1,b0,b1,c0,c1,d0,d1;
    ldK(kg * 512, 0, a0, a1); ldK(kg * 512, 1, b0, b1);
    ldV(kg * 512, 0, c0, c1); ldV(kg * 512, 1, d0, d1);
    stK(0, a0, a1); stK(1, b0, b1); stV(0, c0, c1); stV(1, d0, d1);
  }
  __syncthreads();

  for (int ks = 0; ks < 16; ++ks) {
    const int kb = kg * 512 + ks * 32;

    // T14: issue next tile's global loads before compute
    bf16x8 nk0h,nk0l,nk1h,nk1l,nv0h,nv0l,nv1h,nv1l;
    const bool pfm = (ks + 1) < 16;
    if (pfm) {
      ldK(kb + 32, 0, nk0h, nk0l); ldK(kb + 32, 1, nk1h, nk1l);
      ldV(kb + 32, 0, nv0h, nv0l); ldV(kb + 32, 1, nv1h, nv1l);
    }

    // A gate values: agv[r] = A[qmine][kb + (r&3) + 8*(r>>2) + 4*half]
    float agv[16];
    if (AMODE == 1) {   // coalesced from pre-arranged Af
      const float* Ab = Af + ((size_t)(qt * 32 + kg * 16 + ks) * 2048)
                           + (size_t)qw * 1024 + (lane << 2);
      float4 f0 = *(const float4*)(Ab);
      float4 f1 = *(const float4*)(Ab + 256);
      float4 f2 = *(const float4*)(Ab + 512);
      float4 f3 = *(const float4*)(Ab + 768);
#pragma unroll
      for (int e = 0; e < 4; ++e) {
        agv[e] = f0[e]; agv[4+e] = f1[e]; agv[8+e] = f2[e]; agv[12+e] = f3[e];
      }
    } else {            // v5 direct path (fallback)
      const float* Arow = A + (size_t)qmine * kN + kb + 4 * half;
      float4 ag0 = *(const float4*)(Arow);
      float4 ag1 = *(const float4*)(Arow + 8);
      float4 ag2 = *(const float4*)(Arow + 16);
      float4 ag3 = *(const float4*)(Arow + 24);
#pragma unroll
      for (int e = 0; e < 4; ++e) {
        agv[e] = ag0[e]; agv[4+e] = ag1[e]; agv[8+e] = ag2[e]; agv[12+e] = ag3[e];
      }
    }

    // ---- QK^T swapped: lane holds S[k_local(r,half)][q=l31]
    f32x16 sa;
#pragma unroll
    for (int r = 0; r < 16; ++r) sa[r] = 0.f;
#pragma unroll
    for (int c = 0; c < 4; ++c) {
      bf16x8 kh = *(const bf16x8*)&Khg[l31 * 72 + 16 * c + half * 8];
      bf16x8 kl = *(const bf16x8*)&Klg[l31 * 72 + 16 * c + half * 8];
      sa = MFMA32(kh, qh[c],  sa);
      sa = MFMA32(kh, qlo[c], sa);
      sa = MFMA32(kl, qh[c],  sa);
    }

    // ---- defer-max online softmax (stats lane-local, q = l31)
    float sm = sa[0];
#pragma unroll
    for (int r = 1; r < 16; ++r) sm = fmaxf(sm, sa[r]);
    sm = fmaxf(sm, __shfl_xor(sm, 32, 64));
    if (__any(sm > mrun + 8.f)) {
      const float nm = fmaxf(mrun, sm);
      const float f  = __expf(mrun - nm);   // 0 on first tile
      mrun = nm; Z *= f;
#pragma unroll
      for (int r = 0; r < 16; ++r) {
        const float fr = __shfl(f, (r & 3) + 8 * (r >> 2) + 4 * half, 64);
        o0[r] *= fr; o1[r] *= fr;
      }
    }
    float zt = 0.f;
    float pa[16];
#pragma unroll
    for (int r = 0; r < 16; ++r) {
      const float pv = __expf(sa[r] - mrun);
      zt += pv;
      pa[r] = pv * agv[r];
    }
    zt += __shfl_xor(zt, 32, 64);
    Z += zt;

    // ---- pack gated P to bf16 + cross-half exchange -> PV A-frags
    unsigned du[8], su[8];
#pragma unroll
    for (int j = 0; j < 8; ++j) du[j] = pkbf(pa[2*j], pa[2*j+1]);
#pragma unroll
    for (int j = 0; j < 8; ++j) su[j] = (unsigned)__shfl_xor((int)du[j], 32, 64);
    const bool lo = (half == 0);
    i32x4 w0, w1;
    w0[0] = lo ? du[0] : su[2]; w0[1] = lo ? du[1] : su[3];
    w0[2] = lo ? su[0] : du[2]; w0[3] = lo ? su[1] : du[3];
    w1[0] = lo ? du[4] : su[6]; w1[1] = lo ? du[5] : su[7];
    w1[2] = lo ? su[4] : du[6]; w1[3] = lo ? su[5] : du[7];
    bf16x8 pf0 = *(bf16x8*)&w0;
    bf16x8 pf1 = *(bf16x8*)&w1;

    // ---- PV: O[q][d] += P[q][k] V[k][d]
    {
      bf16x8 vh, vl;
      vh = *(const bf16x8*)&Vthg[l31 * 40 + half * 8];
      vl = *(const bf16x8*)&Vtlg[l31 * 40 + half * 8];
      o0 = MFMA32(pf0, vh, o0); o0 = MFMA32(pf0, vl, o0);
      vh = *(const bf16x8*)&Vthg[l31 * 40 + 16 + half * 8];
      vl = *(const bf16x8*)&Vtlg[l31 * 40 + 16 + half * 8];
      o0 = MFMA32(pf1, vh, o0); o0 = MFMA32(pf1, vl, o0);
      vh = *(const bf16x8*)&Vthg[(32 + l31) * 40 + half * 8];
      vl = *(const bf16x8*)&Vtlg[(32 + l31) * 40 + half * 8];
      o1 = MFMA32(pf0, vh, o1); o1 = MFMA32(pf0, vl, o1);
      vh = *(const bf16x8*)&Vthg[(32 + l31) * 40 + 16 + half * 8];
      vl = *(const bf16x8*)&Vtlg[(32 + l31) * 40 + 16 + half * 8];
      o1 = MFMA32(pf1, vh, o1); o1 = MFMA32(pf1, vl, o1);
    }

    __syncthreads();
    if (pfm) {
      stK(0, nk0h, nk0l); stK(1, nk1h, nk1l);
      stV(0, nv0h, nv0l); stV(1, nv1h, nv1l);
    }
    __syncthreads();
  }

  // ================= split-K merge (v5-verified) =================
  if (lane < 32) {
    aM[kg * 64 + qw * 32 + l31] = mrun;
    aZ[kg * 64 + qw * 32 + l31] = Z;
  }
  if (kg == 1) {
#pragma unroll
    for (int r = 0; r < 16; ++r) {
      const int qq = qw * 32 + (r & 3) + 8 * (r >> 2) + 4 * half;
      Har[qq * 68 + l31]      = o0[r];
      Har[qq * 68 + l31 + 32] = o1[r];
    }
  }
  __syncthreads();
  if (kg == 1 && lane < 32) {
    const int q = qw * 32 + l31;
    const float ma = aM[q], mb = mrun;
    const float m  = fmaxf(ma, mb);
    const float fa = __expf(ma - m), fb = __expf(mb - m);
    const float Zs = aZ[q] * fa + Z * fb;
    aF[q]       = fa;
    aF[64 + q]  = fb;
    aF[128 + q] = 1.0f / (8.0f * Zs);   // sqrt(64)=8
  }
  __syncthreads();
  if (kg == 0) {
#pragma unroll
    for (int r = 0; r < 16; ++r) {
      const int qq = qw * 32 + (r & 3) + 8 * (r >> 2) + 4 * half;
      const float fa = aF[qq], fb = aF[64 + qq];
      Har[qq * 68 + l31]      = o0[r] * fa + Har[qq * 68 + l31]      * fb;
      Har[qq * 68 + l31 + 32] = o1[r] * fa + Har[qq * 68 + l31 + 32] * fb;
    }
  }
  __syncthreads();

  // ================= epilogue (v2-verified 16x16 path) =================
  const int g  = lane >> 4;
  const int ql = lane & 15;
  const int er = wave * 16;
  const float i8z = aF[128 + er + ql];

  bf16x8 hh[2], hl[2];
#pragma unroll
  for (int kk = 0; kk < 2; ++kk) {
    const float* hp = &Har[(er + ql) * 68 + kk * 32 + g * 8];
    float4 v0 = *(const float4*)hp;
    float4 v1 = *(const float4*)(hp + 4);
    float v[8] = {v0.x*i8z, v0.y*i8z, v0.z*i8z, v0.w*i8z,
                  v1.x*i8z, v1.y*i8z, v1.z*i8z, v1.w*i8z};
#pragma unroll
    for (int e = 0; e < 8; ++e) { short a, b; splitv(v[e], a, b); hh[kk][e] = a; hl[kk][e] = b; }
  }

  f32x4 lin[4];
#pragma unroll
  for (int c = 0; c < 4; ++c) {
    bf16x8 wh[2], wl[2];
#pragma unroll
    for (int kk = 0; kk < 2; ++kk) {
      const float* wp = W + (size_t)(c * 16 + ql) * kD + kk * 32 + g * 8;
      float4 v0 = *(const float4*)wp;
      float4 v1 = *(const float4*)(wp + 4);
      float v[8] = {v0.x, v0.y, v0.z, v0.w, v1.x, v1.y, v1.z, v1.w};
#pragma unroll
      for (int e = 0; e < 8; ++e) { short a, b; splitv(v[e], a, b); wh[kk][e] = a; wl[kk][e] = b; }
    }
    f32x4 acc = {0.f, 0.f, 0.f, 0.f};
    acc = MFMA16(hh[0], wh[0], acc);
    acc = MFMA16(hh[1], wh[1], acc);
    acc = MFMA16(hh[0], wl[0], acc);
    acc = MFMA16(hh[1], wl[1], acc);
    acc = MFMA16(hl[0], wh[0], acc);
    acc = MFMA16(hl[1], wh[1], acc);
    lin[c] = acc;
  }

  float rl[4][4];
#pragma unroll
  for (int c = 0; c < 4; ++c)
#pragma unroll
    for (int r = 0; r < 4; ++r) rl[c][r] = fmaxf(lin[c][r], 0.f);

  float mu[4], rstd[4];
#pragma unroll
  for (int r = 0; r < 4; ++r) {
    float s1 = rl[0][r] + rl[1][r] + rl[2][r] + rl[3][r];
    float s2 = rl[0][r]*rl[0][r] + rl[1][r]*rl[1][r] + rl[2][r]*rl[2][r] + rl[3][r]*rl[3][r];
#pragma unroll
    for (int off = 1; off < 16; off <<= 1) {
      s1 += __shfl_xor(s1, off, 64);
      s2 += __shfl_xor(s2, off, 64);
    }
    mu[r] = s1 * (1.f / 64.f);
    const float var = s2 * (1.f / 64.f) - mu[r] * mu[r];
    rstd[r] = rsqrtf(var + 1e-5f);
  }

#pragma unroll
  for (int c = 0; c < 4; ++c) {
    const float gm = gamma[c * 16 + ql];
    const float bb = beta[c * 16 + ql];
#pragma unroll
    for (int r = 0; r < 4; ++r) {
      const int qrow = qblk + er + 4 * g + r;
      const size_t off = ((size_t)bt * kN + qrow) * kD + c * 16 + ql;
      out[off] = (rl[c][r] - mu[r]) * rstd[r] * gm + bb + X[off];
    }
  }
}

extern "C" void kernel_launch(void* const* d_in, const int* in_sizes, int n_in,
                              void* d_out, int out_size, void* d_ws, size_t ws_size,
                              hipStream_t stream) {
  const float* X     = (const float*)d_in[0];
  const float* A     = (const float*)d_in[1];
  const float* W     = (const float*)d_in[2];
  const float* gamma = (const float*)d_in[3];
  const float* beta  = (const float*)d_in[4];
  float* out = (float*)d_out;

  short* Xh  = (short*)d_ws;
  short* Xl  = Xh  + kPlane;
  short* XTh = Xl  + kPlane;
  short* XTl = XTh + kPlane;
  float* Af  = (float*)(XTl + kPlane);

  const size_t need = 4 * kPlane * sizeof(short) + kAfFloats * sizeof(float);

  presplit<<<dim3(48 * 16), 256, 0, stream>>>(X, Xh, Xl, XTh, XTl);
  if (ws_size >= need) {
    prearr_A<<<dim3(16 * 32), 256, 0, stream>>>(A, Af);
    sdgcn_v7<1><<<dim3(48 * 16), 256, 0, stream>>>(X, A, W, gamma, beta, out,
                                                   Xh, Xl, XTh, XTl, Af);
  } else {
    sdgcn_v7<0><<<dim3(48 * 16), 256, 0, stream>>>(X, A, W, gamma, beta, out,
                                                   Xh, Xl, XTh, XTl, Af);
  }
}

// Round 9
// 71.643 us; speedup vs baseline: 2.3934x; 1.1416x over previous
//
#include <hip/hip_runtime.h>
#include <hip/hip_bf16.h>
#include <math.h>

// SDGCN fused, v9 = v8 with the prearr_Abf index-decomposition bug fixed
// (s ranged [0,512) with lane in [0,128) -> OOB writes -> abort; now 256
// items: qw = s>>7, ln = (s>>1)&63, p = s&1).
// Bundle vs v7: XCD-chunked swizzle, V hi-plane only, bf16 prearranged A,
// A prefetch 1 step ahead, setprio around MFMA clusters.
//
// mfma_f32_32x32x16_bf16 layouts (m74/m101-verified C/D; standard A/B):
//   A-frag: lane l holds A[l&31][(l>>5)*8+e]
//   B-frag: lane l holds B[(l>>5)*8+e][l&31]
//   C/D:    lane l, reg r holds C[(r&3)+8*(r>>2)+4*(l>>5)][l&31]

typedef short bf16x8 __attribute__((ext_vector_type(8)));
typedef float f32x4  __attribute__((ext_vector_type(4)));
typedef float f32x16 __attribute__((ext_vector_type(16)));
typedef int   i32x4  __attribute__((ext_vector_type(4)));

constexpr int kN = 1024;
constexpr int kD = 64;
constexpr size_t kPlane    = 48u * 1024u * 64u;        // shorts per bf16 plane
constexpr size_t kAfShorts = 16u * 32u * 2048u;        // prearranged A (bf16)

#define MFMA32(a,b,c) __builtin_amdgcn_mfma_f32_32x32x16_bf16((a),(b),(c),0,0,0)
#define MFMA16(a,b,c) __builtin_amdgcn_mfma_f32_16x16x32_bf16((a),(b),(c),0,0,0)

__device__ __forceinline__ void splitv(float v, short& h, short& l) {
  unsigned u = __float_as_uint(v);
  h = (short)(u >> 16);
  float hf = __uint_as_float(u & 0xFFFF0000u);
  l = (short)(__float_as_uint(v - hf) >> 16);
}

__device__ __forceinline__ unsigned pkbf(float a, float b) {
  return (__float_as_uint(a) >> 16) | (__float_as_uint(b) & 0xFFFF0000u);
}

// ---------------- pre-pass 1: X -> bf16 hi/lo planes (XTl dropped) --------
__global__ __launch_bounds__(256)
void presplit(const float* __restrict__ X, short* __restrict__ Xh,
              short* __restrict__ Xl, short* __restrict__ XTh)
{
  __shared__ short Sh[64][68], Sl[64][68];
  const int t  = threadIdx.x;
  const int bt = blockIdx.x >> 4;
  const int mb = blockIdx.x & 15;
  const size_t base = (size_t)bt * 65536 + (size_t)mb * 64 * 64;

#pragma unroll
  for (int k = 0; k < 4; ++k) {
    int idx = t + k * 256;
    int row = idx >> 4;
    int c4  = (idx & 15) * 4;
    float4 v = *(const float4*)(X + base + row * 64 + c4);
    short h0,l0,h1,l1,h2,l2,h3,l3;
    splitv(v.x, h0, l0); splitv(v.y, h1, l1);
    splitv(v.z, h2, l2); splitv(v.w, h3, l3);
    short4 hv = make_short4(h0, h1, h2, h3);
    short4 lv = make_short4(l0, l1, l2, l3);
    *(short4*)(Xh + base + row * 64 + c4) = hv;
    *(short4*)(Xl + base + row * 64 + c4) = lv;
    *(short4*)&Sh[row][c4] = hv;
    *(short4*)&Sl[row][c4] = lv;
  }
  __syncthreads();

  const size_t tbase = (size_t)bt * 65536 + (size_t)mb * 64;
#pragma unroll
  for (int k = 0; k < 2; ++k) {
    int idx = t + k * 256;
    int d   = idx >> 3;
    int m8  = (idx & 7) * 8;
    bf16x8 hv;
#pragma unroll
    for (int j = 0; j < 8; ++j) hv[j] = Sh[m8 + j][d];
    *(bf16x8*)(XTh + tbase + (size_t)d * 1024 + m8) = hv;
  }
}

// ---------------- pre-pass 2: A -> bf16, per-lane fragment order ----------
// Block (qt, gks) covers k-range [gks*32, gks*32+32). Each of 256 items
// (qw, ln, p) writes 8 shorts: lane ln's v[8p..8p+7] where v[4j+i] =
// bf16(A[qt*64+qw*32+(ln&31)][gks*32 + 8j + 4*(ln>>5) + i]).
__global__ __launch_bounds__(256)
void prearr_Abf(const float* __restrict__ A, short* __restrict__ Af)
{
  const int qt  = blockIdx.x >> 5;
  const int gks = blockIdx.x & 31;
  const int kb  = gks * 32;
  const int s   = threadIdx.x;       // 256 items, one per thread
  short* dst = Af + ((size_t)(qt * 32 + gks) * 2048);

  const int qw = s >> 7;
  const int ln = (s >> 1) & 63;
  const int p  = s & 1;
  const int q  = qt * 64 + qw * 32 + (ln & 31);
  const int h  = ln >> 5;
  const int k0 = kb + 16 * p + 4 * h;
  float4 f0 = *(const float4*)(A + (size_t)q * kN + k0);
  float4 f1 = *(const float4*)(A + (size_t)q * kN + k0 + 8);
  i32x4 u;
  u[0] = (int)pkbf(f0.x, f0.y); u[1] = (int)pkbf(f0.z, f0.w);
  u[2] = (int)pkbf(f1.x, f1.y); u[3] = (int)pkbf(f1.z, f1.w);
  *(i32x4*)(dst + (size_t)qw * 1024 + ln * 16 + p * 8) = u;
}

// ---------------- main fused kernel ----------------
template<int AMODE>
__global__ __launch_bounds__(256)
void sdgcn_v9(const float* __restrict__ X, const float* __restrict__ A,
              const float* __restrict__ W, const float* __restrict__ gamma,
              const float* __restrict__ beta, float* __restrict__ out,
              const short* __restrict__ Xh, const short* __restrict__ Xl,
              const short* __restrict__ XTh, const short* __restrict__ Af)
{
  // LDS 28672B: per kg { Kh[32*72], Kl[32*72] shorts @ kg*9216 ;
  //                      Vth[64*40] shorts @ 18432 + kg*5120 }
  // post-loop union: aM/aZ/aF (1792B @0), Har[64][68] f32 @1792.
  __shared__ __align__(16) unsigned char LB[28672];

  const int t    = threadIdx.x;
  const int wave = t >> 6;
  const int lane = t & 63;
  const int kg   = wave >> 1;
  const int qw   = wave & 1;
  const int half = lane >> 5;
  const int l31  = lane & 31;
  // XCD-chunked swizzle: 768 = 8 XCD * 96; each XCD gets 6 consecutive bt.
  const int bid  = blockIdx.x;
  const int swz  = (bid & 7) * 96 + (bid >> 3);
  const int bt   = swz >> 4;
  const int qt   = swz & 15;
  const int qblk = qt * 64;
  const size_t xb = (size_t)bt * 65536;

  short* Khg  = (short*)(LB + kg * 9216);
  short* Klg  = Khg + 2304;
  short* Vthg = (short*)(LB + 18432 + kg * 5120);
  float* aM   = (float*)LB;             // [2][64]
  float* aZ   = aM + 128;
  float* aF   = aZ + 128;               // [3][64]
  float* Har  = (float*)(LB + 1792);    // [64][68]

  // ---- Q B-frags
  const int qmine = qblk + qw * 32 + l31;
  bf16x8 qh[4], qlo[4];
#pragma unroll
  for (int c = 0; c < 4; ++c) {
    const size_t off = xb + (size_t)qmine * kD + 16 * c + half * 8;
    qh[c]  = *(const bf16x8*)(Xh + off);
    qlo[c] = *(const bf16x8*)(Xl + off);
  }

  f32x16 o0, o1;
#pragma unroll
  for (int r = 0; r < 16; ++r) { o0[r] = 0.f; o1[r] = 0.f; }
  float mrun = -INFINITY, Z = 0.f;

  const int tg = t & 127;

  auto ldK = [&](int kb, int j, bf16x8& h, bf16x8& l) {
    int ck = tg + 128 * j; int kr = ck >> 3; int kc = (ck & 7) * 8;
    size_t off = xb + (size_t)(kb + kr) * kD + kc;
    h = *(const bf16x8*)(Xh + off);
    l = *(const bf16x8*)(Xl + off);
  };
  auto ldV = [&](int kb, int j, bf16x8& h) {
    int cv = tg + 128 * j; int vd = cv >> 2; int vm = (cv & 3) * 8;
    h = *(const bf16x8*)(XTh + xb + (size_t)vd * 1024 + kb + vm);
  };
  auto stK = [&](int j, bf16x8 h, bf16x8 l) {
    int ck = tg + 128 * j; int kr = ck >> 3; int kc = (ck & 7) * 8;
    *(bf16x8*)&Khg[kr * 72 + kc] = h;
    *(bf16x8*)&Klg[kr * 72 + kc] = l;
  };
  auto stV = [&](int j, bf16x8 h) {
    int cv = tg + 128 * j; int vd = cv >> 2; int vm = (cv & 3) * 8;
    *(bf16x8*)&Vthg[vd * 40 + vm] = h;
  };

  // prologue: stage tile 0 of this k-group; load A(step 0)
  {
    bf16x8 a0,a1,b0,b1,c0,d0;
    ldK(kg * 512, 0, a0, a1); ldK(kg * 512, 1, b0, b1);
    ldV(kg * 512, 0, c0);     ldV(kg * 512, 1, d0);
    stK(0, a0, a1); stK(1, b0, b1); stV(0, c0); stV(1, d0);
  }
  i32x4 aA = {0,0,0,0}, aB = {0,0,0,0};
  if (AMODE == 1) {
    const short* Ab = Af + ((size_t)(qt * 32 + kg * 16) * 2048)
                         + (size_t)qw * 1024 + (lane << 4);
    aA = *(const i32x4*)(Ab);
    aB = *(const i32x4*)(Ab + 8);
  }
  __syncthreads();

  for (int ks = 0; ks < 16; ++ks) {
    const int kb = kg * 512 + ks * 32;
    const bool pfm = (ks + 1) < 16;

    // T14: issue next tile's K/V and next step's A early
    bf16x8 nk0h,nk0l,nk1h,nk1l,nv0,nv1;
    if (pfm) {
      ldK(kb + 32, 0, nk0h, nk0l); ldK(kb + 32, 1, nk1h, nk1l);
      ldV(kb + 32, 0, nv0);        ldV(kb + 32, 1, nv1);
    }
    i32x4 naA = {0,0,0,0}, naB = {0,0,0,0};
    if (AMODE == 1 && pfm) {
      const short* Ab = Af + ((size_t)(qt * 32 + kg * 16 + ks + 1) * 2048)
                           + (size_t)qw * 1024 + (lane << 4);
      naA = *(const i32x4*)(Ab);
      naB = *(const i32x4*)(Ab + 8);
    }

    // A gate: agv[r] = A[qmine][kb + (r&3) + 8*(r>>2) + 4*half]
    float agv[16];
    if (AMODE == 1) {
      unsigned u[8] = {(unsigned)aA[0],(unsigned)aA[1],(unsigned)aA[2],(unsigned)aA[3],
                       (unsigned)aB[0],(unsigned)aB[1],(unsigned)aB[2],(unsigned)aB[3]};
#pragma unroll
      for (int m = 0; m < 8; ++m) {
        agv[2*m]   = __uint_as_float(u[m] << 16);
        agv[2*m+1] = __uint_as_float(u[m] & 0xFFFF0000u);
      }
    } else {
      const float* Arow = A + (size_t)qmine * kN + kb + 4 * half;
      float4 ag0 = *(const float4*)(Arow);
      float4 ag1 = *(const float4*)(Arow + 8);
      float4 ag2 = *(const float4*)(Arow + 16);
      float4 ag3 = *(const float4*)(Arow + 24);
#pragma unroll
      for (int e = 0; e < 4; ++e) {
        agv[e] = ag0[e]; agv[4+e] = ag1[e]; agv[8+e] = ag2[e]; agv[12+e] = ag3[e];
      }
    }

    // ---- QK^T swapped: lane holds S[k_local(r,half)][q=l31]
    f32x16 sa;
#pragma unroll
    for (int r = 0; r < 16; ++r) sa[r] = 0.f;
    __builtin_amdgcn_s_setprio(1);
#pragma unroll
    for (int c = 0; c < 4; ++c) {
      bf16x8 kh = *(const bf16x8*)&Khg[l31 * 72 + 16 * c + half * 8];
      bf16x8 kl = *(const bf16x8*)&Klg[l31 * 72 + 16 * c + half * 8];
      sa = MFMA32(kh, qh[c],  sa);
      sa = MFMA32(kh, qlo[c], sa);
      sa = MFMA32(kl, qh[c],  sa);
    }
    __builtin_amdgcn_s_setprio(0);

    // ---- defer-max online softmax (stats lane-local, q = l31)
    float sm = sa[0];
#pragma unroll
    for (int r = 1; r < 16; ++r) sm = fmaxf(sm, sa[r]);
    sm = fmaxf(sm, __shfl_xor(sm, 32, 64));
    if (__any(sm > mrun + 8.f)) {
      const float nm = fmaxf(mrun, sm);
      const float f  = __expf(mrun - nm);   // 0 on first tile
      mrun = nm; Z *= f;
#pragma unroll
      for (int r = 0; r < 16; ++r) {
        const float fr = __shfl(f, (r & 3) + 8 * (r >> 2) + 4 * half, 64);
        o0[r] *= fr; o1[r] *= fr;
      }
    }
    float zt = 0.f;
    float pa[16];
#pragma unroll
    for (int r = 0; r < 16; ++r) {
      const float pv = __expf(sa[r] - mrun);
      zt += pv;
      pa[r] = pv * agv[r];
    }
    zt += __shfl_xor(zt, 32, 64);
    Z += zt;

    // ---- pack gated P to bf16 + cross-half exchange -> PV A-frags
    unsigned du[8], su[8];
#pragma unroll
    for (int j = 0; j < 8; ++j) du[j] = pkbf(pa[2*j], pa[2*j+1]);
#pragma unroll
    for (int j = 0; j < 8; ++j) su[j] = (unsigned)__shfl_xor((int)du[j], 32, 64);
    const bool lo = (half == 0);
    i32x4 w0, w1;
    w0[0] = lo ? du[0] : su[2]; w0[1] = lo ? du[1] : su[3];
    w0[2] = lo ? su[0] : du[2]; w0[3] = lo ? su[1] : du[3];
    w1[0] = lo ? du[4] : su[6]; w1[1] = lo ? du[5] : su[7];
    w1[2] = lo ? su[4] : du[6]; w1[3] = lo ? su[5] : du[7];
    bf16x8 pf0 = *(bf16x8*)&w0;
    bf16x8 pf1 = *(bf16x8*)&w1;

    // ---- PV: O[q][d] += P[q][k] V[k][d]   (V hi-plane only)
    {
      bf16x8 v0 = *(const bf16x8*)&Vthg[l31 * 40 + half * 8];
      bf16x8 v1 = *(const bf16x8*)&Vthg[l31 * 40 + 16 + half * 8];
      bf16x8 v2 = *(const bf16x8*)&Vthg[(32 + l31) * 40 + half * 8];
      bf16x8 v3 = *(const bf16x8*)&Vthg[(32 + l31) * 40 + 16 + half * 8];
      __builtin_amdgcn_s_setprio(1);
      o0 = MFMA32(pf0, v0, o0);
      o0 = MFMA32(pf1, v1, o0);
      o1 = MFMA32(pf0, v2, o1);
      o1 = MFMA32(pf1, v3, o1);
      __builtin_amdgcn_s_setprio(0);
    }

    __syncthreads();
    if (pfm) {
      stK(0, nk0h, nk0l); stK(1, nk1h, nk1l);
      stV(0, nv0);        stV(1, nv1);
    }
    __syncthreads();
    aA = naA; aB = naB;
  }

  // ================= split-K merge (v5-verified) =================
  if (lane < 32) {
    aM[kg * 64 + qw * 32 + l31] = mrun;
    aZ[kg * 64 + qw * 32 + l31] = Z;
  }
  if (kg == 1) {
#pragma unroll
    for (int r = 0; r < 16; ++r) {
      const int qq = qw * 32 + (r & 3) + 8 * (r >> 2) + 4 * half;
      Har[qq * 68 + l31]      = o0[r];
      Har[qq * 68 + l31 + 32] = o1[r];
    }
  }
  __syncthreads();
  if (kg == 1 && lane < 32) {
    const int q = qw * 32 + l31;
    const float ma = aM[q], mb = mrun;
    const float m  = fmaxf(ma, mb);
    const float fa = __expf(ma - m), fb = __expf(mb - m);
    const float Zs = aZ[q] * fa + Z * fb;
    aF[q]       = fa;
    aF[64 + q]  = fb;
    aF[128 + q] = 1.0f / (8.0f * Zs);   // sqrt(64)=8
  }
  __syncthreads();
  if (kg == 0) {
#pragma unroll
    for (int r = 0; r < 16; ++r) {
      const int qq = qw * 32 + (r & 3) + 8 * (r >> 2) + 4 * half;
      const float fa = aF[qq], fb = aF[64 + qq];
      Har[qq * 68 + l31]      = o0[r] * fa + Har[qq * 68 + l31]      * fb;
      Har[qq * 68 + l31 + 32] = o1[r] * fa + Har[qq * 68 + l31 + 32] * fb;
    }
  }
  __syncthreads();

  // ================= epilogue (v2-verified 16x16 path) =================
  const int g  = lane >> 4;
  const int ql = lane & 15;
  const int er = wave * 16;
  const float i8z = aF[128 + er + ql];

  bf16x8 hh[2], hl[2];
#pragma unroll
  for (int kk = 0; kk < 2; ++kk) {
    const float* hp = &Har[(er + ql) * 68 + kk * 32 + g * 8];
    float4 v0 = *(const float4*)hp;
    float4 v1 = *(const float4*)(hp + 4);
    float v[8] = {v0.x*i8z, v0.y*i8z, v0.z*i8z, v0.w*i8z,
                  v1.x*i8z, v1.y*i8z, v1.z*i8z, v1.w*i8z};
#pragma unroll
    for (int e = 0; e < 8; ++e) { short a, b; splitv(v[e], a, b); hh[kk][e] = a; hl[kk][e] = b; }
  }

  f32x4 lin[4];
#pragma unroll
  for (int c = 0; c < 4; ++c) {
    bf16x8 wh[2], wl[2];
#pragma unroll
    for (int kk = 0; kk < 2; ++kk) {
      const float* wp = W + (size_t)(c * 16 + ql) * kD + kk * 32 + g * 8;
      float4 v0 = *(const float4*)wp;
      float4 v1 = *(const float4*)(wp + 4);
      float v[8] = {v0.x, v0.y, v0.z, v0.w, v1.x, v1.y, v1.z, v1.w};
#pragma unroll
      for (int e = 0; e < 8; ++e) { short a, b; splitv(v[e], a, b); wh[kk][e] = a; wl[kk][e] = b; }
    }
    f32x4 acc = {0.f, 0.f, 0.f, 0.f};
    acc = MFMA16(hh[0], wh[0], acc);
    acc = MFMA16(hh[1], wh[1], acc);
    acc = MFMA16(hh[0], wl[0], acc);
    acc = MFMA16(hh[1], wl[1], acc);
    acc = MFMA16(hl[0], wh[0], acc);
    acc = MFMA16(hl[1], wh[1], acc);
    lin[c] = acc;
  }

  float rl[4][4];
#pragma unroll
  for (int c = 0; c < 4; ++c)
#pragma unroll
    for (int r = 0; r < 4; ++r) rl[c][r] = fmaxf(lin[c][r], 0.f);

  float mu[4], rstd[4];
#pragma unroll
  for (int r = 0; r < 4; ++r) {
    float s1 = rl[0][r] + rl[1][r] + rl[2][r] + rl[3][r];
    float s2 = rl[0][r]*rl[0][r] + rl[1][r]*rl[1][r] + rl[2][r]*rl[2][r] + rl[3][r]*rl[3][r];
#pragma unroll
    for (int off = 1; off < 16; off <<= 1) {
      s1 += __shfl_xor(s1, off, 64);
      s2 += __shfl_xor(s2, off, 64);
    }
    mu[r] = s1 * (1.f / 64.f);
    const float var = s2 * (1.f / 64.f) - mu[r] * mu[r];
    rstd[r] = rsqrtf(var + 1e-5f);
  }

#pragma unroll
  for (int c = 0; c < 4; ++c) {
    const float gm = gamma[c * 16 + ql];
    const float bb = beta[c * 16 + ql];
#pragma unroll
    for (int r = 0; r < 4; ++r) {
      const int qrow = qblk + er + 4 * g + r;
      const size_t off = ((size_t)bt * kN + qrow) * kD + c * 16 + ql;
      out[off] = (rl[c][r] - mu[r]) * rstd[r] * gm + bb + X[off];
    }
  }
}

extern "C" void kernel_launch(void* const* d_in, const int* in_sizes, int n_in,
                              void* d_out, int out_size, void* d_ws, size_t ws_size,
                              hipStream_t stream) {
  const float* X     = (const float*)d_in[0];
  const float* A     = (const float*)d_in[1];
  const float* W     = (const float*)d_in[2];
  const float* gamma = (const float*)d_in[3];
  const float* beta  = (const float*)d_in[4];
  float* out = (float*)d_out;

  short* Xh  = (short*)d_ws;
  short* Xl  = Xh  + kPlane;
  short* XTh = Xl  + kPlane;
  short* Af  = XTh + kPlane;

  const size_t need = (3 * kPlane + kAfShorts) * sizeof(short);

  presplit<<<dim3(48 * 16), 256, 0, stream>>>(X, Xh, Xl, XTh);
  if (ws_size >= need) {
    prearr_Abf<<<dim3(16 * 32), 256, 0, stream>>>(A, Af);
    sdgcn_v9<1><<<dim3(48 * 16), 256, 0, stream>>>(X, A, W, gamma, beta, out,
                                                   Xh, Xl, XTh, Af);
  } else {
    sdgcn_v9<0><<<dim3(48 * 16), 256, 0, stream>>>(X, A, W, gamma, beta, out,
                                                   Xh, Xl, XTh, Af);
  }
}